// Round 16
// baseline (317.688 us; speedup 1.0000x reference)
//
#include <hip/hip_runtime.h>
#include <hip/hip_bf16.h>

#define DEVI __device__ __forceinline__

constexpr int NN = 10000;       // nodes
constexpr int NE = 80000;       // edges
constexpr int AGG_ROWS = 10240; // 32*320 and 64*160 — both M-tilings stay in-bounds
constexpr int ES_CAP = 110016;  // NE + 3*NN padded-CSR capacity, rounded up

typedef __attribute__((ext_vector_type(8))) short bf16x8;    // 8 bf16 (4 VGPRs)
typedef __attribute__((ext_vector_type(4))) float f32x4;     // 16x16 MFMA acc
typedef __attribute__((ext_vector_type(16))) float f32x16;   // 32x32 MFMA acc

// ---------- bf16 helpers (bit-level, RNE) ----------
DEVI float blo(unsigned int u) {
  union { unsigned int i; float f; } c; c.i = u << 16; return c.f;
}
DEVI float bhi(unsigned int u) {
  union { unsigned int i; float f; } c; c.i = u & 0xffff0000u; return c.f;
}
DEVI unsigned short f2b(float f) {
  union { float f; unsigned int i; } c; c.f = f;
  unsigned int i = c.i;
  return (unsigned short)((i + 0x7fffu + ((i >> 16) & 1u)) >> 16);
}
DEVI void st1(float* p, float v) { *p = v; }
DEVI void st1(unsigned short* p, float v) { *p = f2b(v); }
DEVI void store8b(unsigned short* p, const float v[8]) {
  int4 pk;
  pk.x = (int)((unsigned)f2b(v[0]) | ((unsigned)f2b(v[1]) << 16));
  pk.y = (int)((unsigned)f2b(v[2]) | ((unsigned)f2b(v[3]) << 16));
  pk.z = (int)((unsigned)f2b(v[4]) | ((unsigned)f2b(v[5]) << 16));
  pk.w = (int)((unsigned)f2b(v[6]) | ((unsigned)f2b(v[7]) << 16));
  *reinterpret_cast<int4*>(p) = pk;
}

// async global->LDS, 16B per lane (wave-uniform LDS base + lane*16 pattern)
DEVI void gload16(const void* g, void* l) {
  __builtin_amdgcn_global_load_lds(
      (const __attribute__((address_space(1))) void*)g,
      (__attribute__((address_space(3))) void*)l, 16, 0, 0);
}

// ================= CSR build =================
__global__ __launch_bounds__(256)
void hist_kernel(const int* __restrict__ dst, int* __restrict__ cnt) {
  int e = blockIdx.x * 256 + threadIdx.x;
  if (e < NE) atomicAdd(&cnt[dst[e]], 1);
}

// exclusive scan of PADDED counts ((cnt+3)&~3) -> off, cursor.
__global__ __launch_bounds__(1024)
void scan_kernel(const int* __restrict__ cnt, int* __restrict__ off,
                 int* __restrict__ cursor) {
  __shared__ int wpart[16];
  __shared__ int carry;
  int tid = threadIdx.x, lane = tid & 63, w = tid >> 6;
  if (tid == 0) carry = 0;
  __syncthreads();
  for (int base = 0; base < NN; base += 1024) {
    int i = base + tid;
    int v = (i < NN) ? ((cnt[i] + 3) & ~3) : 0;
    int s = v;
#pragma unroll
    for (int o = 1; o < 64; o <<= 1) { int t = __shfl_up(s, o); if (lane >= o) s += t; }
    if (lane == 63) wpart[w] = s;
    __syncthreads();
    if (w == 0) {
      int ws = (lane < 16) ? wpart[lane] : 0;
#pragma unroll
      for (int o = 1; o < 16; o <<= 1) { int t = __shfl_up(ws, o); if (lane >= o) ws += t; }
      if (lane < 16) wpart[lane] = ws;
    }
    __syncthreads();
    int ex = carry + (w ? wpart[w - 1] : 0) + s - v;   // exclusive prefix
    if (i < NN) { off[i] = ex; cursor[i] = ex; }
    __syncthreads();
    if (tid == 0) carry += wpart[15];
    __syncthreads();
  }
}

// bucket: es[p] = src, rel[p] = pos[src]-pos[dst]. es pre-zeroed so pad slots
// hold node 0 (valid address); their FMAs are guarded off by cnt.
__global__ __launch_bounds__(256)
void bucket_kernel(const int* __restrict__ src, const int* __restrict__ dst,
                   const float* __restrict__ pos,
                   int* __restrict__ cursor, int* __restrict__ es,
                   float* __restrict__ rel) {
  int e = blockIdx.x * 256 + threadIdx.x;
  if (e < NE) {
    int s = src[e], d = dst[e];
    int p = atomicAdd(&cursor[d], 1);
    float2 ps = *reinterpret_cast<const float2*>(pos + 2 * s);
    float2 pd = *reinterpret_cast<const float2*>(pos + 2 * d);
    es[p] = s;
    *reinterpret_cast<float2*>(rel + 2 * p) = make_float2(ps.x - pd.x, ps.y - pd.y);
  }
}

// ============ weight convert+transpose: W[K][N] f32 -> WT[N][K] bf16 ============
__global__ __launch_bounds__(256)
void transpose_w(const float* __restrict__ W, unsigned short* __restrict__ WT,
                 int K, int N) {
  __shared__ float tile[32][33];
  int tx = threadIdx.x & 31, ty = threadIdx.x >> 5;  // ty 0..7
  int n0 = blockIdx.x * 32, k0 = blockIdx.y * 32;
#pragma unroll
  for (int j = 0; j < 32; j += 8)
    tile[ty + j][tx] = W[(size_t)(k0 + ty + j) * N + n0 + tx];
  __syncthreads();
#pragma unroll
  for (int j = 0; j < 32; j += 8)
    WT[(size_t)(n0 + ty + j) * K + k0 + tx] = f2b(tile[tx][ty + j]);
}

// ================= gather-aggregate (CSR, no atomics, int4 src fan-out) =================
// layer 1: C=128, x f32. One 64-lane wave per node, 2 ch/lane. bf16 out.
__global__ __launch_bounds__(256)
void gather_l1(const float* __restrict__ x,
               const int* __restrict__ off, const int* __restrict__ cnt,
               const int* __restrict__ es, const float* __restrict__ rel,
               const float* __restrict__ Win, const float* __restrict__ bin,
               unsigned short* __restrict__ agg) {
  constexpr int C = 128;
  int lane = threadIdx.x & 63;
  int i = blockIdx.x * 4 + (threadIdx.x >> 6);
  if (i >= NN) return;
  int c = lane * 2;
  float w00 = Win[c], w01 = Win[c + 1];
  float w10 = Win[C + c], w11 = Win[C + c + 1];
  float b0 = bin[c], b1 = bin[c + 1];
  float a0 = 0.f, a1 = 0.f;
  int s0 = off[i], n = cnt[i];   // s0 % 4 == 0 (padded CSR)

  for (int k = 0; k < n; k += 4) {
    int4 s4 = *reinterpret_cast<const int4*>(es + s0 + k);
    float4 ra = *reinterpret_cast<const float4*>(rel + 2 * (s0 + k));
    float4 rb = *reinterpret_cast<const float4*>(rel + 2 * (s0 + k) + 4);
    float2 q0 = *reinterpret_cast<const float2*>(x + (size_t)s4.x * C + c);
    float2 q1 = *reinterpret_cast<const float2*>(x + (size_t)s4.y * C + c);
    float2 q2 = *reinterpret_cast<const float2*>(x + (size_t)s4.z * C + c);
    float2 q3 = *reinterpret_cast<const float2*>(x + (size_t)s4.w * C + c);
    {
      float sc0 = fmaxf(fmaf(ra.x, w00, fmaf(ra.y, w10, b0)), 0.f);
      float sc1 = fmaxf(fmaf(ra.x, w01, fmaf(ra.y, w11, b1)), 0.f);
      a0 = fmaf(sc0, q0.x, a0); a1 = fmaf(sc1, q0.y, a1);
    }
    if (k + 1 < n) {
      float sc0 = fmaxf(fmaf(ra.z, w00, fmaf(ra.w, w10, b0)), 0.f);
      float sc1 = fmaxf(fmaf(ra.z, w01, fmaf(ra.w, w11, b1)), 0.f);
      a0 = fmaf(sc0, q1.x, a0); a1 = fmaf(sc1, q1.y, a1);
    }
    if (k + 2 < n) {
      float sc0 = fmaxf(fmaf(rb.x, w00, fmaf(rb.y, w10, b0)), 0.f);
      float sc1 = fmaxf(fmaf(rb.x, w01, fmaf(rb.y, w11, b1)), 0.f);
      a0 = fmaf(sc0, q2.x, a0); a1 = fmaf(sc1, q2.y, a1);
    }
    if (k + 3 < n) {
      float sc0 = fmaxf(fmaf(rb.z, w00, fmaf(rb.w, w10, b0)), 0.f);
      float sc1 = fmaxf(fmaf(rb.z, w01, fmaf(rb.w, w11, b1)), 0.f);
      a0 = fmaf(sc0, q3.x, a0); a1 = fmaf(sc1, q3.y, a1);
    }
  }
  unsigned int pk = (unsigned)f2b(a0) | ((unsigned)f2b(a1) << 16);
  *reinterpret_cast<unsigned int*>(agg + (size_t)i * C + c) = pk;
}

// layers 2/3: C=2048, 16 XCD-affine chunks of 128 ch. Block = 4 waves = 16
// node-slots; 16 lanes/node x 8 ch (16B loads). int4 src fan-out: one es
// load -> 4 independent x-row loads (real ILP the compiler can't collapse).
__global__ __launch_bounds__(256)
void gather_chunk(const unsigned short* __restrict__ x,
                  const int* __restrict__ off, const int* __restrict__ cnt,
                  const int* __restrict__ es, const float* __restrict__ rel,
                  const float* __restrict__ Win, const float* __restrict__ bin,
                  unsigned short* __restrict__ agg, int ngb8) {
  constexpr int C = 2048;
  constexpr int V = 8;
  int wgid = blockIdx.x;
  int half = wgid >= ngb8;
  int base = half ? wgid - ngb8 : wgid;
  int chunk = (base & 7) + (half << 3);     // 0..15
  int grp = base >> 3;                      // 0..624
  int lane = threadIdx.x & 63;
  int wid = threadIdx.x >> 6;
  int slot = lane >> 4;
  int l16 = lane & 15;
  int i = grp * 16 + wid * 4 + slot;        // 625*16 == 10000: always < NN
  int c = chunk * 128 + l16 * V;

  float w0[V], w1[V], bb[V], acc[V];
#pragma unroll
  for (int j = 0; j < V; ++j) {
    w0[j] = Win[c + j]; w1[j] = Win[C + c + j]; bb[j] = bin[c + j]; acc[j] = 0.f;
  }
  int s0 = off[i], n = cnt[i];   // s0 % 4 == 0 (padded CSR)

  auto fma8 = [&](float rx, float ry, const int4& q) {
    float xv[V] = { blo(q.x), bhi(q.x), blo(q.y), bhi(q.y),
                    blo(q.z), bhi(q.z), blo(q.w), bhi(q.w) };
#pragma unroll
    for (int j = 0; j < V; ++j) {
      float sc = fmaxf(fmaf(rx, w0[j], fmaf(ry, w1[j], bb[j])), 0.f);
      acc[j] = fmaf(sc, xv[j], acc[j]);
    }
  };
  for (int k = 0; k < n; k += 4) {
    int4 s4 = *reinterpret_cast<const int4*>(es + s0 + k);
    float4 ra = *reinterpret_cast<const float4*>(rel + 2 * (s0 + k));
    float4 rb = *reinterpret_cast<const float4*>(rel + 2 * (s0 + k) + 4);
    int4 q0 = *reinterpret_cast<const int4*>(x + (size_t)s4.x * C + c);
    int4 q1 = *reinterpret_cast<const int4*>(x + (size_t)s4.y * C + c);
    int4 q2 = *reinterpret_cast<const int4*>(x + (size_t)s4.z * C + c);
    int4 q3 = *reinterpret_cast<const int4*>(x + (size_t)s4.w * C + c);
    fma8(ra.x, ra.y, q0);
    if (k + 1 < n) fma8(ra.z, ra.w, q1);
    if (k + 2 < n) fma8(rb.x, rb.y, q2);
    if (k + 3 < n) fma8(rb.z, rb.w, q3);
  }
  store8b(agg + (size_t)i * C + c, acc);
}

// ============ 320x256 8-wave MFMA GEMM, 32x32x16, BK=64 (GEMM1/2) ============
// out = relu(A[M,K] @ BT[N,K]^T + bias). A, BT bf16 (ushort).
// MECHANISM (r15 analysis): 2-barrier wall = LDS-port time + MFMA time
// serialized. mfma_32x32x16 doubles FLOP per LDS frag-byte (wave 160x64 =
// 5x2 of 32x32: 2926 FLOP/B vs 2276) -> LDS term drops ~2x.
// Staging = r14's validated 320x256/BK=64 scheme verbatim: 9 passes of
// 512thr x 16B, linear dest, source k-chunk = slot ^ (row&7) (8-slot XOR,
// 128B rows). 32-row frag reads are bank-UNIFORM under this swizzle:
// 8 lanes/slot x 4 banks = exact 8-word/bank minimum.
// Frag layout: A/B lane = row (lane&31), k-half (lane>>5)*8 (16x16-verified
// convention scaled); C/D: col=lane&31, row=(reg&3)+8*(reg>>2)+4*(lane>>5)
// [m74/m101 verified]. acc 5x2 f32x16 = 160 regs (~205 total < 256 cap).
// Grid: GEMM1/2 8x32 = 256 blocks = ONE exact round at 1 block/CU.
template <typename OT>
__global__ __launch_bounds__(512, 2)
void gemm3232(const unsigned short* __restrict__ A,
              const unsigned short* __restrict__ BT,
              const float* __restrict__ bias, OT* __restrict__ out,
              int M, int N, int K) {
  extern __shared__ unsigned short lds[];   // 2 bufs x 36864 ush (73728 B each)
  const int t = threadIdx.x;
  const int lane = t & 63, wid = t >> 6;    // 8 waves
  const int wr = wid >> 2, wc = wid & 3;    // 2M x 4N, wave-tile 160x64

  // XCD-chunked bijective swizzle (nwg % 8 == 0 for all our grids)
  const int nwg = gridDim.x * gridDim.y;
  const int orig = blockIdx.y * gridDim.x + blockIdx.x;
  const int swz = (orig & 7) * (nwg >> 3) + (orig >> 3);
  const int bx = swz % gridDim.x, by = swz / gridDim.x;
  const int m0 = by * 320, n0 = bx * 256;
  const int nk = K >> 6;

  // staging (r14-validated): thread t -> row-in-pass t>>3, stored slot t&7,
  // source k-chunk = slot ^ (row&7). A: 5 passes (320 rows); B: 4 (256).
  const int srow = t >> 3;                  // 0..63
  const int schunk = (t & 7) ^ (srow & 7);
  const unsigned short* gA = A + (size_t)(m0 + srow) * K + schunk * 8;
  const unsigned short* gB = BT + (size_t)(n0 + srow) * K + schunk * 8;
  const int lt8 = t * 8;                    // ush offset within pass

  auto STAGE = [&](int buf, int kt) {
    const size_t ko = (size_t)kt << 6;
    unsigned short* lb = lds + buf * 36864;
#pragma unroll
    for (int jj = 0; jj < 5; ++jj)
      gload16(gA + (size_t)(jj * 64) * K + ko, lb + jj * 4096 + lt8);
#pragma unroll
    for (int jj = 0; jj < 4; ++jj)
      gload16(gB + (size_t)(jj * 64) * K + ko, lb + 20480 + jj * 4096 + lt8);
  };

  // fragment reads (32x32): row = base + frow32 (bases ≡ 0 mod 8), K-16 step
  // ks: chunk = ks*2 + (lane>>5); slot = chunk ^ (frow32&7); elem off slot*8.
  const int frow32 = lane & 31, cb = lane >> 5;
  const int fr7 = frow32 & 7;
  const int paRow = (wr * 160 + frow32) * 64;          // + m*2048
  const int pbRow = 20480 + (wc * 64 + frow32) * 64;   // + n*2048

  f32x16 acc[5][2];
#pragma unroll
  for (int m = 0; m < 5; ++m)
#pragma unroll
    for (int n = 0; n < 2; ++n)
#pragma unroll
      for (int r = 0; r < 16; ++r) acc[m][n][r] = 0.f;

  STAGE(0, 0);  // prologue: 9 loads outstanding

  int cur = 0;
  for (int kt = 0; kt < nk; ++kt) {
    if (kt + 1 < nk) {
      STAGE(cur ^ 1, kt + 1);                           // freed by prev trailing barrier
      asm volatile("s_waitcnt vmcnt(9)" ::: "memory");  // kt's 9 landed; 9 in flight
    } else {
      asm volatile("s_waitcnt vmcnt(0)" ::: "memory");
    }
    asm volatile("s_barrier" ::: "memory");             // publish tile kt
    const unsigned short* pa = lds + cur * 36864 + paRow;
    const unsigned short* pb = lds + cur * 36864 + pbRow;
#pragma unroll
    for (int ks = 0; ks < 4; ++ks) {
      const int sl = (((ks << 1) | cb) ^ fr7) * 8;
      bf16x8 af[5], bf[2];
#pragma unroll
      for (int n = 0; n < 2; ++n)
        bf[n] = *reinterpret_cast<const bf16x8*>(pb + n * 2048 + sl);
#pragma unroll
      for (int m = 0; m < 5; ++m)
        af[m] = *reinterpret_cast<const bf16x8*>(pa + m * 2048 + sl);
      __builtin_amdgcn_s_setprio(1);
#pragma unroll
      for (int m = 0; m < 5; ++m)
#pragma unroll
        for (int n = 0; n < 2; ++n)
          acc[m][n] = __builtin_amdgcn_mfma_f32_32x32x16_bf16(
              af[m], bf[n], acc[m][n], 0, 0, 0);
      __builtin_amdgcn_s_setprio(0);
    }
    asm volatile("s_barrier" ::: "memory");  // reads of cur done before overwrite
    cur ^= 1;
  }

  // epilogue: 32x32 C/D layout col=lane&31, row=(reg&3)+8*(reg>>2)+4*(lane>>5)
  const int ccol = lane & 31;
  const int crow4 = (lane >> 5) * 4;
  float bv[2];
#pragma unroll
  for (int n = 0; n < 2; ++n)
    bv[n] = bias[n0 + wc * 64 + n * 32 + ccol];
#pragma unroll
  for (int m = 0; m < 5; ++m) {
    const int gmBase = m0 + wr * 160 + m * 32 + crow4;
#pragma unroll
    for (int r = 0; r < 16; ++r) {
      int gm = gmBase + (r & 3) + 8 * (r >> 2);
      if (gm < M) {
        size_t base = (size_t)gm * N + n0 + wc * 64 + ccol;
#pragma unroll
        for (int n = 0; n < 2; ++n)
          st1(out + base + n * 32, fmaxf(acc[m][n][r] + bv[n], 0.f));
      }
    }
  }
}

// ============ 160x128 4-wave MFMA GEMM, BK=64 (round-7 proven, GEMM3) ============
template <typename OT>
__global__ __launch_bounds__(256, 2)
void gemm160(const unsigned short* __restrict__ A,
             const unsigned short* __restrict__ BT,
             const float* __restrict__ bias, OT* __restrict__ out,
             int M, int N, int K) {
  extern __shared__ unsigned short lds[];  // A: [2][10240] @0; B: [2][8192] @20480
  const int t = threadIdx.x;
  const int lane = t & 63, wid = t >> 6;
  const int wr = wid >> 1, wc = wid & 1;          // 2x2 wave grid, 80x64 each

  const int nwg = gridDim.x * gridDim.y;
  const int orig = blockIdx.y * gridDim.x + blockIdx.x;
  const int swz = (orig & 7) * (nwg >> 3) + (orig >> 3);
  const int bx = swz % gridDim.x, by = swz / gridDim.x;
  const int m0 = by * 160, n0 = bx * 128;
  const int nk = K >> 6;

  const int lrow = lane >> 3;              // 0..7
  const int schunk = (lane & 7) ^ lrow;    // pre-swizzled source k-chunk
  const unsigned short* gA = A + (size_t)(m0 + wid * 40 + lrow) * K + schunk * 8;
  const unsigned short* gB = BT + (size_t)(n0 + wid * 32 + lrow) * K + schunk * 8;
  unsigned short* lA = lds + (wid * 5) * 512 + lane * 8;          // +jj*512
  unsigned short* lB = lds + 20480 + (wid * 4) * 512 + lane * 8;  // +jj*512

  auto STAGE = [&](int buf, int kt) {
    const size_t ko = (size_t)kt << 6;
#pragma unroll
    for (int jj = 0; jj < 5; ++jj)
      gload16(gA + (size_t)(jj * 8) * K + ko, lA + buf * 10240 + jj * 512);
#pragma unroll
    for (int jj = 0; jj < 4; ++jj)
      gload16(gB + (size_t)(jj * 8) * K + ko, lB + buf * 8192 + jj * 512);
  };

  const int frow = lane & 15;
  const int fr7 = frow & 7;
  const int slot0 = ((lane >> 4) ^ fr7) * 8;        // ks=0
  const int slot1 = ((4 + (lane >> 4)) ^ fr7) * 8;  // ks=1
  const int paRow = (wr * 80 + frow) * 64;
  const int pbRow = (wc * 64 + frow) * 64;

  f32x4 acc[5][4];
#pragma unroll
  for (int m = 0; m < 5; ++m)
#pragma unroll
    for (int n = 0; n < 4; ++n) acc[m][n] = 0.f;

  STAGE(0, 0);  // prologue: 9 loads outstanding

  int cur = 0;
  for (int kt = 0; kt < nk; ++kt) {
    if (kt + 1 < nk) {
      STAGE(cur ^ 1, kt + 1);
      asm volatile("s_waitcnt vmcnt(9)" ::: "memory");  // kt's 9 loads landed
    } else {
      asm volatile("s_waitcnt vmcnt(0)" ::: "memory");
    }
    asm volatile("s_barrier" ::: "memory");  // all waves: tile kt staged
    const unsigned short* pa = lds + cur * 10240 + paRow;
    const unsigned short* pb = lds + 20480 + cur * 8192 + pbRow;
#pragma unroll
    for (int ks = 0; ks < 2; ++ks) {
      const int sl = ks ? slot1 : slot0;
      bf16x8 af[5], bf[4];
#pragma unroll
      for (int m = 0; m < 5; ++m)
        af[m] = *reinterpret_cast<const bf16x8*>(pa + m * 1024 + sl);
#pragma unroll
      for (int n = 0; n < 4; ++n)
        bf[n] = *reinterpret_cast<const bf16x8*>(pb + n * 1024 + sl);
      __builtin_amdgcn_s_setprio(1);
#pragma unroll
      for (int m = 0; m < 5; ++m)
#pragma unroll
        for (int n = 0; n < 4; ++n)
          acc[m][n] = __builtin_amdgcn_mfma_f32_16x16x32_bf16(
              af[m], bf[n], acc[m][n], 0, 0, 0);
      __builtin_amdgcn_s_setprio(0);
    }
    asm volatile("s_barrier" ::: "memory");  // reads done before overwrite
    cur ^= 1;
  }

  // epilogue: C/D layout col=lane&15, row=(lane>>4)*4+reg
  const int ccol = lane & 15;
  const int crow = (lane >> 4) * 4;
  float bv[4];
#pragma unroll
  for (int n = 0; n < 4; ++n)
    bv[n] = bias[n0 + wc * 64 + n * 16 + ccol];
#pragma unroll
  for (int m = 0; m < 5; ++m) {
    int gm0 = m0 + wr * 80 + m * 16 + crow;
#pragma unroll
    for (int r = 0; r < 4; ++r) {
      int gm = gm0 + r;
      if (gm < M) {
        size_t base = (size_t)gm * N + n0 + wc * 64 + ccol;
#pragma unroll
        for (int n = 0; n < 4; ++n)
          st1(out + base + n * 16, fmaxf(acc[m][n][r] + bv[n], 0.f));
      }
    }
  }
}

// ---------- row-wise L2 normalize, C=1024 ----------
__global__ __launch_bounds__(256)
void l2norm_kernel(float* __restrict__ out) {
  constexpr int C = 1024;
  float* p = out + (size_t)blockIdx.x * C;
  float4 v = *reinterpret_cast<const float4*>(p + threadIdx.x * 4);
  float s = v.x * v.x + v.y * v.y + v.z * v.z + v.w * v.w;
#pragma unroll
  for (int o = 32; o > 0; o >>= 1) s += __shfl_down(s, o);
  __shared__ float wsum[4];
  if ((threadIdx.x & 63) == 0) wsum[threadIdx.x >> 6] = s;
  __syncthreads();
  float tot = wsum[0] + wsum[1] + wsum[2] + wsum[3];
  float inv = 1.0f / fmaxf(sqrtf(tot), 1e-12f);
  float4 r = make_float4(v.x * inv, v.y * inv, v.z * inv, v.w * inv);
  *reinterpret_cast<float4*>(p + threadIdx.x * 4) = r;
}

extern "C" void kernel_launch(void* const* d_in, const int* in_sizes, int n_in,
                              void* d_out, int out_size, void* d_ws, size_t ws_size,
                              hipStream_t stream) {
  (void)in_sizes; (void)n_in; (void)out_size; (void)ws_size;
  const float* x     = (const float*)d_in[0];
  const float* pos   = (const float*)d_in[1];
  const int*   ei    = (const int*)d_in[2];
  const int*   srcv  = ei;            // edge_index[0] (j)
  const int*   dstv  = ei + NE;       // edge_index[1] (i)
  const float* Win1  = (const float*)d_in[3];
  const float* bin1  = (const float*)d_in[4];
  const float* Wout1 = (const float*)d_in[5];
  const float* bout1 = (const float*)d_in[6];
  const float* Win2  = (const float*)d_in[7];
  const float* bin2  = (const float*)d_in[8];
  const float* Wout2 = (const float*)d_in[9];
  const float* bout2 = (const float*)d_in[10];
  const float* Win3  = (const float*)d_in[11];
  const float* bin3  = (const float*)d_in[12];
  const float* Wout3 = (const float*)d_in[13];
  const float* bout3 = (const float*)d_in[14];
  float* outp = (float*)d_out;

  // workspace layout (~97.5 MB; 123 MB proven safe in round 1)
  char* ws = (char*)d_ws;
  unsigned short* aggb = (unsigned short*)ws;                    // 10240*2048*2 = 41,943,040
  unsigned short* h1   = (unsigned short*)(ws + 41943040);       // 10000*2048*2 = 40,960,000
  unsigned short* W2T  = (unsigned short*)(ws + 82903040);       // 2048*2048*2  =  8,388,608
  unsigned short* W3T  = (unsigned short*)(ws + 91291648);       // 1024*2048*2  =  4,194,304
  unsigned short* W1T  = (unsigned short*)(ws + 95485952);       // 2048*128*2   =    524,288
  int* cnt    = (int*)(ws + 96010240);
  int* off    = (int*)(ws + 96050240);
  int* cursor = (int*)(ws + 96090240);
  int* es     = (int*)(ws + 96130240);                           // ES_CAP*4 = 440,064
  float* rel  = (float*)(ws + 96570304);                         // ES_CAP*8 = 880,128
  // h2 bf16 [NN,2048] = 40,960,000 B lives in d_out; dead before GEMM3 overwrites it
  unsigned short* h2 = (unsigned short*)d_out;

  // dynamic LDS attributes (host-side, graph-capture safe, proven round 3)
  hipFuncSetAttribute((const void*)gemm3232<unsigned short>,
                      hipFuncAttributeMaxDynamicSharedMemorySize, 147456);
  hipFuncSetAttribute((const void*)gemm160<float>,
                      hipFuncAttributeMaxDynamicSharedMemorySize, 73728);

  const dim3 blk(256);
  const int eb = (NE + 255) / 256;
  const int ngb8 = ((NN + 15) / 16) * 8;   // 5000; gather_chunk grid = 2*ngb8

  // ---- CSR build (padded segments) + edge rel/src packing ----
  hipMemsetAsync(cnt, 0, NN * sizeof(int), stream);
  hipMemsetAsync(es, 0, ES_CAP * sizeof(int), stream);  // pad slots -> node 0 (safe addr)
  hist_kernel<<<eb, blk, 0, stream>>>(dstv, cnt);
  scan_kernel<<<1, 1024, 0, stream>>>(cnt, off, cursor);
  bucket_kernel<<<eb, blk, 0, stream>>>(srcv, dstv, pos, cursor, es, rel);

  // ---- weight transposes (f32 -> bf16, [K][N] -> [N][K]) ----
  transpose_w<<<dim3(2048 / 32, 128 / 32),  blk, 0, stream>>>(Wout1, W1T, 128, 2048);
  transpose_w<<<dim3(2048 / 32, 2048 / 32), blk, 0, stream>>>(Wout2, W2T, 2048, 2048);
  transpose_w<<<dim3(1024 / 32, 2048 / 32), blk, 0, stream>>>(Wout3, W3T, 2048, 1024);

  // zero the 240 pad rows of aggb once per call (gathers never touch them)
  hipMemsetAsync(aggb + (size_t)NN * 2048, 0, (size_t)(AGG_ROWS - NN) * 2048 * 2, stream);

  // ---- layer 1: 128 -> 2048 ----
  gather_l1<<<(NN + 3) / 4, blk, 0, stream>>>(x, off, cnt, es, rel, Win1, bin1, aggb);
  gemm3232<unsigned short><<<dim3(2048 / 256, AGG_ROWS / 320), 512, 147456, stream>>>(
      aggb, W1T, bout1, h1, NN, 2048, 128);

  // ---- layer 2: 2048 -> 2048 ----
  gather_chunk<<<2 * ngb8, blk, 0, stream>>>(h1, off, cnt, es, rel, Win2, bin2, aggb, ngb8);
  gemm3232<unsigned short><<<dim3(2048 / 256, AGG_ROWS / 320), 512, 147456, stream>>>(
      aggb, W2T, bout2, h2, NN, 2048, 2048);

  // ---- layer 3: 2048 -> 1024 (gemm160: 512 blocks = 2/CU, one exact round) ----
  gather_chunk<<<2 * ngb8, blk, 0, stream>>>(h2, off, cnt, es, rel, Win3, bin3, aggb, ngb8);
  gemm160<float><<<dim3(1024 / 128, AGG_ROWS / 160), blk, 73728, stream>>>(
      aggb, W3T, bout3, outp, NN, 1024, 2048);

  // ---- final L2 normalize ----
  l2norm_kernel<<<NN, blk, 0, stream>>>(outp);
}

// Round 17
// 309.218 us; speedup vs baseline: 1.0274x; 1.0274x over previous
//
#include <hip/hip_runtime.h>
#include <hip/hip_bf16.h>

#define DEVI __device__ __forceinline__

constexpr int NN = 10000;       // nodes
constexpr int NE = 80000;       // edges
constexpr int AGG_ROWS = 10240; // 32*320 and 64*160 — both M-tilings stay in-bounds
constexpr int ES_CAP = 110016;  // NE + 3*NN padded-CSR capacity, rounded up

typedef __attribute__((ext_vector_type(8))) short bf16x8;  // 8 bf16 (4 VGPRs)
typedef __attribute__((ext_vector_type(4))) float f32x4;   // MFMA acc

// ---------- bf16 helpers (bit-level, RNE) ----------
DEVI float blo(unsigned int u) {
  union { unsigned int i; float f; } c; c.i = u << 16; return c.f;
}
DEVI float bhi(unsigned int u) {
  union { unsigned int i; float f; } c; c.i = u & 0xffff0000u; return c.f;
}
DEVI unsigned short f2b(float f) {
  union { float f; unsigned int i; } c; c.f = f;
  unsigned int i = c.i;
  return (unsigned short)((i + 0x7fffu + ((i >> 16) & 1u)) >> 16);
}
DEVI void st1(float* p, float v) { *p = v; }
DEVI void st1(unsigned short* p, float v) { *p = f2b(v); }
DEVI void store8b(unsigned short* p, const float v[8]) {
  int4 pk;
  pk.x = (int)((unsigned)f2b(v[0]) | ((unsigned)f2b(v[1]) << 16));
  pk.y = (int)((unsigned)f2b(v[2]) | ((unsigned)f2b(v[3]) << 16));
  pk.z = (int)((unsigned)f2b(v[4]) | ((unsigned)f2b(v[5]) << 16));
  pk.w = (int)((unsigned)f2b(v[6]) | ((unsigned)f2b(v[7]) << 16));
  *reinterpret_cast<int4*>(p) = pk;
}

// async global->LDS, 16B per lane (wave-uniform LDS base + lane*16 pattern)
DEVI void gload16(const void* g, void* l) {
  __builtin_amdgcn_global_load_lds(
      (const __attribute__((address_space(1))) void*)g,
      (__attribute__((address_space(3))) void*)l, 16, 0, 0);
}

// ================= CSR build =================
__global__ __launch_bounds__(256)
void hist_kernel(const int* __restrict__ dst, int* __restrict__ cnt) {
  int e = blockIdx.x * 256 + threadIdx.x;
  if (e < NE) atomicAdd(&cnt[dst[e]], 1);
}

// exclusive scan of PADDED counts ((cnt+3)&~3) -> off, cursor.
__global__ __launch_bounds__(1024)
void scan_kernel(const int* __restrict__ cnt, int* __restrict__ off,
                 int* __restrict__ cursor) {
  __shared__ int wpart[16];
  __shared__ int carry;
  int tid = threadIdx.x, lane = tid & 63, w = tid >> 6;
  if (tid == 0) carry = 0;
  __syncthreads();
  for (int base = 0; base < NN; base += 1024) {
    int i = base + tid;
    int v = (i < NN) ? ((cnt[i] + 3) & ~3) : 0;
    int s = v;
#pragma unroll
    for (int o = 1; o < 64; o <<= 1) { int t = __shfl_up(s, o); if (lane >= o) s += t; }
    if (lane == 63) wpart[w] = s;
    __syncthreads();
    if (w == 0) {
      int ws = (lane < 16) ? wpart[lane] : 0;
#pragma unroll
      for (int o = 1; o < 16; o <<= 1) { int t = __shfl_up(ws, o); if (lane >= o) ws += t; }
      if (lane < 16) wpart[lane] = ws;
    }
    __syncthreads();
    int ex = carry + (w ? wpart[w - 1] : 0) + s - v;   // exclusive prefix
    if (i < NN) { off[i] = ex; cursor[i] = ex; }
    __syncthreads();
    if (tid == 0) carry += wpart[15];
    __syncthreads();
  }
}

// bucket: es[p] = src, rel[p] = pos[src]-pos[dst]. es pre-zeroed so pad slots
// hold node 0 (valid address); their FMAs are guarded off by cnt.
__global__ __launch_bounds__(256)
void bucket_kernel(const int* __restrict__ src, const int* __restrict__ dst,
                   const float* __restrict__ pos,
                   int* __restrict__ cursor, int* __restrict__ es,
                   float* __restrict__ rel) {
  int e = blockIdx.x * 256 + threadIdx.x;
  if (e < NE) {
    int s = src[e], d = dst[e];
    int p = atomicAdd(&cursor[d], 1);
    float2 ps = *reinterpret_cast<const float2*>(pos + 2 * s);
    float2 pd = *reinterpret_cast<const float2*>(pos + 2 * d);
    es[p] = s;
    *reinterpret_cast<float2*>(rel + 2 * p) = make_float2(ps.x - pd.x, ps.y - pd.y);
  }
}

// ==== fused weight convert+transpose: three W[K][N] f32 -> WT[N][K] bf16 ====
// one launch, flattened 1D grid; tile 32x32. ranges: W1 256, W2 4096, W3 2048.
__global__ __launch_bounds__(256)
void transpose_w3(const float* __restrict__ W1, unsigned short* __restrict__ T1,
                  const float* __restrict__ W2, unsigned short* __restrict__ T2,
                  const float* __restrict__ W3, unsigned short* __restrict__ T3) {
  __shared__ float tile[32][33];
  int b = blockIdx.x;
  const float* W; unsigned short* WT; int K, N, bx, by;
  if (b < 256)        { W = W1; WT = T1; K = 128;  N = 2048; b -= 0;
                        bx = b & 63;  by = b >> 6; }   // 64 x 4
  else if (b < 4352)  { W = W2; WT = T2; K = 2048; N = 2048; b -= 256;
                        bx = b & 63;  by = b >> 6; }   // 64 x 64
  else                { W = W3; WT = T3; K = 2048; N = 1024; b -= 4352;
                        bx = b & 31;  by = b >> 5; }   // 32 x 64
  int tx = threadIdx.x & 31, ty = threadIdx.x >> 5;    // ty 0..7
  int n0 = bx * 32, k0 = by * 32;
#pragma unroll
  for (int j = 0; j < 32; j += 8)
    tile[ty + j][tx] = W[(size_t)(k0 + ty + j) * N + n0 + tx];
  __syncthreads();
#pragma unroll
  for (int j = 0; j < 32; j += 8)
    WT[(size_t)(n0 + ty + j) * K + k0 + tx] = f2b(tile[tx][ty + j]);
}

// ================= gather-aggregate (CSR, no atomics, int4 src fan-out) =================
// layer 1: C=128, x f32. One 64-lane wave per node, 2 ch/lane. bf16 out.
__global__ __launch_bounds__(256)
void gather_l1(const float* __restrict__ x,
               const int* __restrict__ off, const int* __restrict__ cnt,
               const int* __restrict__ es, const float* __restrict__ rel,
               const float* __restrict__ Win, const float* __restrict__ bin,
               unsigned short* __restrict__ agg) {
  constexpr int C = 128;
  int lane = threadIdx.x & 63;
  int i = blockIdx.x * 4 + (threadIdx.x >> 6);
  if (i >= NN) return;
  int c = lane * 2;
  float w00 = Win[c], w01 = Win[c + 1];
  float w10 = Win[C + c], w11 = Win[C + c + 1];
  float b0 = bin[c], b1 = bin[c + 1];
  float a0 = 0.f, a1 = 0.f;
  int s0 = off[i], n = cnt[i];   // s0 % 4 == 0 (padded CSR)

  for (int k = 0; k < n; k += 4) {
    int4 s4 = *reinterpret_cast<const int4*>(es + s0 + k);
    float4 ra = *reinterpret_cast<const float4*>(rel + 2 * (s0 + k));
    float4 rb = *reinterpret_cast<const float4*>(rel + 2 * (s0 + k) + 4);
    float2 q0 = *reinterpret_cast<const float2*>(x + (size_t)s4.x * C + c);
    float2 q1 = *reinterpret_cast<const float2*>(x + (size_t)s4.y * C + c);
    float2 q2 = *reinterpret_cast<const float2*>(x + (size_t)s4.z * C + c);
    float2 q3 = *reinterpret_cast<const float2*>(x + (size_t)s4.w * C + c);
    {
      float sc0 = fmaxf(fmaf(ra.x, w00, fmaf(ra.y, w10, b0)), 0.f);
      float sc1 = fmaxf(fmaf(ra.x, w01, fmaf(ra.y, w11, b1)), 0.f);
      a0 = fmaf(sc0, q0.x, a0); a1 = fmaf(sc1, q0.y, a1);
    }
    if (k + 1 < n) {
      float sc0 = fmaxf(fmaf(ra.z, w00, fmaf(ra.w, w10, b0)), 0.f);
      float sc1 = fmaxf(fmaf(ra.z, w01, fmaf(ra.w, w11, b1)), 0.f);
      a0 = fmaf(sc0, q1.x, a0); a1 = fmaf(sc1, q1.y, a1);
    }
    if (k + 2 < n) {
      float sc0 = fmaxf(fmaf(rb.x, w00, fmaf(rb.y, w10, b0)), 0.f);
      float sc1 = fmaxf(fmaf(rb.x, w01, fmaf(rb.y, w11, b1)), 0.f);
      a0 = fmaf(sc0, q2.x, a0); a1 = fmaf(sc1, q2.y, a1);
    }
    if (k + 3 < n) {
      float sc0 = fmaxf(fmaf(rb.z, w00, fmaf(rb.w, w10, b0)), 0.f);
      float sc1 = fmaxf(fmaf(rb.z, w01, fmaf(rb.w, w11, b1)), 0.f);
      a0 = fmaf(sc0, q3.x, a0); a1 = fmaf(sc1, q3.y, a1);
    }
  }
  unsigned int pk = (unsigned)f2b(a0) | ((unsigned)f2b(a1) << 16);
  *reinterpret_cast<unsigned int*>(agg + (size_t)i * C + c) = pk;
}

// layers 2/3: C=2048, 16 XCD-affine chunks of 128 ch. Block = 4 waves = 16
// node-slots; 16 lanes/node x 8 ch (16B loads). int4 src fan-out: one es
// load -> 4 independent x-row loads (real ILP the compiler can't collapse).
__global__ __launch_bounds__(256)
void gather_chunk(const unsigned short* __restrict__ x,
                  const int* __restrict__ off, const int* __restrict__ cnt,
                  const int* __restrict__ es, const float* __restrict__ rel,
                  const float* __restrict__ Win, const float* __restrict__ bin,
                  unsigned short* __restrict__ agg, int ngb8) {
  constexpr int C = 2048;
  constexpr int V = 8;
  int wgid = blockIdx.x;
  int half = wgid >= ngb8;
  int base = half ? wgid - ngb8 : wgid;
  int chunk = (base & 7) + (half << 3);     // 0..15
  int grp = base >> 3;                      // 0..624
  int lane = threadIdx.x & 63;
  int wid = threadIdx.x >> 6;
  int slot = lane >> 4;
  int l16 = lane & 15;
  int i = grp * 16 + wid * 4 + slot;        // 625*16 == 10000: always < NN
  int c = chunk * 128 + l16 * V;

  float w0[V], w1[V], bb[V], acc[V];
#pragma unroll
  for (int j = 0; j < V; ++j) {
    w0[j] = Win[c + j]; w1[j] = Win[C + c + j]; bb[j] = bin[c + j]; acc[j] = 0.f;
  }
  int s0 = off[i], n = cnt[i];   // s0 % 4 == 0 (padded CSR)

  auto fma8 = [&](float rx, float ry, const int4& q) {
    float xv[V] = { blo(q.x), bhi(q.x), blo(q.y), bhi(q.y),
                    blo(q.z), bhi(q.z), blo(q.w), bhi(q.w) };
#pragma unroll
    for (int j = 0; j < V; ++j) {
      float sc = fmaxf(fmaf(rx, w0[j], fmaf(ry, w1[j], bb[j])), 0.f);
      acc[j] = fmaf(sc, xv[j], acc[j]);
    }
  };
  for (int k = 0; k < n; k += 4) {
    int4 s4 = *reinterpret_cast<const int4*>(es + s0 + k);
    float4 ra = *reinterpret_cast<const float4*>(rel + 2 * (s0 + k));
    float4 rb = *reinterpret_cast<const float4*>(rel + 2 * (s0 + k) + 4);
    int4 q0 = *reinterpret_cast<const int4*>(x + (size_t)s4.x * C + c);
    int4 q1 = *reinterpret_cast<const int4*>(x + (size_t)s4.y * C + c);
    int4 q2 = *reinterpret_cast<const int4*>(x + (size_t)s4.z * C + c);
    int4 q3 = *reinterpret_cast<const int4*>(x + (size_t)s4.w * C + c);
    fma8(ra.x, ra.y, q0);
    if (k + 1 < n) fma8(ra.z, ra.w, q1);
    if (k + 2 < n) fma8(rb.x, rb.y, q2);
    if (k + 3 < n) fma8(rb.z, rb.w, q3);
  }
  store8b(agg + (size_t)i * C + c, acc);
}

// ============ 320x128 8-wave MFMA GEMM, BK=32 (round-12/15 proven, GEMM1/2) ============
// 8 waves (4M x 2N), wave-tile 80x64; launch_bounds(512,4) -> 2 blocks/CU.
// Row-major LDS + 4-slot XOR swizzle (0 conflicts), 64B-coalesced staging,
// counted vmcnt (role-split: A-waves 5, B-waves 2), raw s_barrier, setprio.
// Grids: GEMM1/2 16x32 = 512 blocks = ONE exact round at 2 blocks/CU.
template <typename OT>
__global__ __launch_bounds__(512, 4)
void gemm320(const unsigned short* __restrict__ A,
             const unsigned short* __restrict__ BT,
             const float* __restrict__ bias, OT* __restrict__ out,
             int M, int N, int K) {
  __shared__ unsigned short lds[2 * 14336];  // per buf: A 10240 ushorts, B 4096
  const int t = threadIdx.x;
  const int lane = t & 63, wid = t >> 6;          // 0..7
  const int wr = wid >> 1, wc = wid & 1;          // 4x2 wave grid, 80x64 each

  // XCD-chunked bijective swizzle (nwg % 8 == 0 for all our grids)
  const int nwg = gridDim.x * gridDim.y;
  const int orig = blockIdx.y * gridDim.x + blockIdx.x;
  const int swz = (orig & 7) * (nwg >> 3) + (orig >> 3);
  const int bx = swz % gridDim.x, by = swz / gridDim.x;
  const int m0 = by * 320, n0 = bx * 128;
  const int nk = K >> 5;

  const int lrow = lane >> 2;                      // 0..15
  const int schunk = (lane & 3) ^ ((lrow >> 1) & 3);
  const bool isA = wid < 4;
  const int aw = wid & 3;
  const unsigned short* gSrc = isA
      ? A + (size_t)(m0 + aw * 80 + lrow) * K + schunk * 8
      : BT + (size_t)(n0 + aw * 32 + lrow) * K + schunk * 8;
  const int lBase = isA ? (aw * 5 * 512 + lane * 8)
                        : (10240 + aw * 2 * 512 + lane * 8);

  auto STAGE = [&](int buf, int kt) {
    const unsigned short* g = gSrc + kt * 32;
    unsigned short* l = lds + buf * 14336 + lBase;
    if (isA) {
#pragma unroll
      for (int jj = 0; jj < 5; ++jj)
        gload16(g + (size_t)(jj * 16) * K, l + jj * 512);
    } else {
#pragma unroll
      for (int jj = 0; jj < 2; ++jj)
        gload16(g + (size_t)(jj * 16) * K, l + jj * 512);
    }
  };

  const int frow = lane & 15;
  const int fslot = ((lane >> 4) ^ ((frow >> 1) & 3)) * 8;
  const int paOff = (wr * 80 + frow) * 32 + fslot;
  const int pbOff = 10240 + (wc * 64 + frow) * 32 + fslot;

  f32x4 acc[5][4];
#pragma unroll
  for (int m = 0; m < 5; ++m)
#pragma unroll
    for (int n = 0; n < 4; ++n) acc[m][n] = 0.f;

  STAGE(0, 0);  // prologue

  int cur = 0;
  for (int kt = 0; kt < nk; ++kt) {
    if (kt + 1 < nk) {
      STAGE(cur ^ 1, kt + 1);
      if (isA) asm volatile("s_waitcnt vmcnt(5)" ::: "memory");
      else     asm volatile("s_waitcnt vmcnt(2)" ::: "memory");
    } else {
      asm volatile("s_waitcnt vmcnt(0)" ::: "memory");
    }
    asm volatile("s_barrier" ::: "memory");  // all waves: tile kt staged
    const unsigned short* pa = lds + cur * 14336 + paOff;
    const unsigned short* pb = lds + cur * 14336 + pbOff;
    bf16x8 bf[4];
#pragma unroll
    for (int n = 0; n < 4; ++n)
      bf[n] = *reinterpret_cast<const bf16x8*>(pb + n * 512);
    __builtin_amdgcn_s_setprio(1);
#pragma unroll
    for (int m = 0; m < 5; ++m) {
      bf16x8 af = *reinterpret_cast<const bf16x8*>(pa + m * 512);
#pragma unroll
      for (int n = 0; n < 4; ++n)
        acc[m][n] = __builtin_amdgcn_mfma_f32_16x16x32_bf16(
            af, bf[n], acc[m][n], 0, 0, 0);
    }
    __builtin_amdgcn_s_setprio(0);
    asm volatile("s_barrier" ::: "memory");  // reads done before overwrite
    cur ^= 1;
  }

  // epilogue: C/D layout col=lane&15, row=(lane>>4)*4+reg
  const int ccol = lane & 15;
  const int crow = (lane >> 4) * 4;
  float bv[4];
#pragma unroll
  for (int n = 0; n < 4; ++n)
    bv[n] = bias[n0 + wc * 64 + n * 16 + ccol];
#pragma unroll
  for (int m = 0; m < 5; ++m) {
    int gm0 = m0 + wr * 80 + m * 16 + crow;
#pragma unroll
    for (int r = 0; r < 4; ++r) {
      int gm = gm0 + r;
      if (gm < M) {
        size_t base = (size_t)gm * N + n0 + wc * 64 + ccol;
#pragma unroll
        for (int n = 0; n < 4; ++n)
          st1(out + base + n * 16, fmaxf(acc[m][n][r] + bv[n], 0.f));
      }
    }
  }
}

// ============ 160x128 4-wave MFMA GEMM, BK=64 (round-7 proven, GEMM3) ============
template <typename OT>
__global__ __launch_bounds__(256, 2)
void gemm160(const unsigned short* __restrict__ A,
             const unsigned short* __restrict__ BT,
             const float* __restrict__ bias, OT* __restrict__ out,
             int M, int N, int K) {
  extern __shared__ unsigned short lds[];  // A: [2][10240] @0; B: [2][8192] @20480
  const int t = threadIdx.x;
  const int lane = t & 63, wid = t >> 6;
  const int wr = wid >> 1, wc = wid & 1;          // 2x2 wave grid, 80x64 each

  const int nwg = gridDim.x * gridDim.y;
  const int orig = blockIdx.y * gridDim.x + blockIdx.x;
  const int swz = (orig & 7) * (nwg >> 3) + (orig >> 3);
  const int bx = swz % gridDim.x, by = swz / gridDim.x;
  const int m0 = by * 160, n0 = bx * 128;
  const int nk = K >> 6;

  const int lrow = lane >> 3;              // 0..7
  const int schunk = (lane & 7) ^ lrow;    // pre-swizzled source k-chunk
  const unsigned short* gA = A + (size_t)(m0 + wid * 40 + lrow) * K + schunk * 8;
  const unsigned short* gB = BT + (size_t)(n0 + wid * 32 + lrow) * K + schunk * 8;
  unsigned short* lA = lds + (wid * 5) * 512 + lane * 8;          // +jj*512
  unsigned short* lB = lds + 20480 + (wid * 4) * 512 + lane * 8;  // +jj*512

  auto STAGE = [&](int buf, int kt) {
    const size_t ko = (size_t)kt << 6;
#pragma unroll
    for (int jj = 0; jj < 5; ++jj)
      gload16(gA + (size_t)(jj * 8) * K + ko, lA + buf * 10240 + jj * 512);
#pragma unroll
    for (int jj = 0; jj < 4; ++jj)
      gload16(gB + (size_t)(jj * 8) * K + ko, lB + buf * 8192 + jj * 512);
  };

  const int frow = lane & 15;
  const int fr7 = frow & 7;
  const int slot0 = ((lane >> 4) ^ fr7) * 8;        // ks=0
  const int slot1 = ((4 + (lane >> 4)) ^ fr7) * 8;  // ks=1
  const int paRow = (wr * 80 + frow) * 64;
  const int pbRow = (wc * 64 + frow) * 64;

  f32x4 acc[5][4];
#pragma unroll
  for (int m = 0; m < 5; ++m)
#pragma unroll
    for (int n = 0; n < 4; ++n) acc[m][n] = 0.f;

  STAGE(0, 0);  // prologue: 9 loads outstanding

  int cur = 0;
  for (int kt = 0; kt < nk; ++kt) {
    if (kt + 1 < nk) {
      STAGE(cur ^ 1, kt + 1);
      asm volatile("s_waitcnt vmcnt(9)" ::: "memory");  // kt's 9 loads landed
    } else {
      asm volatile("s_waitcnt vmcnt(0)" ::: "memory");
    }
    asm volatile("s_barrier" ::: "memory");  // all waves: tile kt staged
    const unsigned short* pa = lds + cur * 10240 + paRow;
    const unsigned short* pb = lds + 20480 + cur * 8192 + pbRow;
#pragma unroll
    for (int ks = 0; ks < 2; ++ks) {
      const int sl = ks ? slot1 : slot0;
      bf16x8 af[5], bf[4];
#pragma unroll
      for (int m = 0; m < 5; ++m)
        af[m] = *reinterpret_cast<const bf16x8*>(pa + m * 1024 + sl);
#pragma unroll
      for (int n = 0; n < 4; ++n)
        bf[n] = *reinterpret_cast<const bf16x8*>(pb + n * 1024 + sl);
      __builtin_amdgcn_s_setprio(1);
#pragma unroll
      for (int m = 0; m < 5; ++m)
#pragma unroll
        for (int n = 0; n < 4; ++n)
          acc[m][n] = __builtin_amdgcn_mfma_f32_16x16x32_bf16(
              af[m], bf[n], acc[m][n], 0, 0, 0);
      __builtin_amdgcn_s_setprio(0);
    }
    asm volatile("s_barrier" ::: "memory");  // reads done before overwrite
    cur ^= 1;
  }

  // epilogue: C/D layout col=lane&15, row=(lane>>4)*4+reg
  const int ccol = lane & 15;
  const int crow = (lane >> 4) * 4;
  float bv[4];
#pragma unroll
  for (int n = 0; n < 4; ++n)
    bv[n] = bias[n0 + wc * 64 + n * 16 + ccol];
#pragma unroll
  for (int m = 0; m < 5; ++m) {
    int gm0 = m0 + wr * 80 + m * 16 + crow;
#pragma unroll
    for (int r = 0; r < 4; ++r) {
      int gm = gm0 + r;
      if (gm < M) {
        size_t base = (size_t)gm * N + n0 + wc * 64 + ccol;
#pragma unroll
        for (int n = 0; n < 4; ++n)
          st1(out + base + n * 16, fmaxf(acc[m][n][r] + bv[n], 0.f));
      }
    }
  }
}

// ---------- row-wise L2 normalize, C=1024 ----------
__global__ __launch_bounds__(256)
void l2norm_kernel(float* __restrict__ out) {
  constexpr int C = 1024;
  float* p = out + (size_t)blockIdx.x * C;
  float4 v = *reinterpret_cast<const float4*>(p + threadIdx.x * 4);
  float s = v.x * v.x + v.y * v.y + v.z * v.z + v.w * v.w;
#pragma unroll
  for (int o = 32; o > 0; o >>= 1) s += __shfl_down(s, o);
  __shared__ float wsum[4];
  if ((threadIdx.x & 63) == 0) wsum[threadIdx.x >> 6] = s;
  __syncthreads();
  float tot = wsum[0] + wsum[1] + wsum[2] + wsum[3];
  float inv = 1.0f / fmaxf(sqrtf(tot), 1e-12f);
  float4 r = make_float4(v.x * inv, v.y * inv, v.z * inv, v.w * inv);
  *reinterpret_cast<float4*>(p + threadIdx.x * 4) = r;
}

extern "C" void kernel_launch(void* const* d_in, const int* in_sizes, int n_in,
                              void* d_out, int out_size, void* d_ws, size_t ws_size,
                              hipStream_t stream) {
  (void)in_sizes; (void)n_in; (void)out_size; (void)ws_size;
  const float* x     = (const float*)d_in[0];
  const float* pos   = (const float*)d_in[1];
  const int*   ei    = (const int*)d_in[2];
  const int*   srcv  = ei;            // edge_index[0] (j)
  const int*   dstv  = ei + NE;       // edge_index[1] (i)
  const float* Win1  = (const float*)d_in[3];
  const float* bin1  = (const float*)d_in[4];
  const float* Wout1 = (const float*)d_in[5];
  const float* bout1 = (const float*)d_in[6];
  const float* Win2  = (const float*)d_in[7];
  const float* bin2  = (const float*)d_in[8];
  const float* Wout2 = (const float*)d_in[9];
  const float* bout2 = (const float*)d_in[10];
  const float* Win3  = (const float*)d_in[11];
  const float* bin3  = (const float*)d_in[12];
  const float* Wout3 = (const float*)d_in[13];
  const float* bout3 = (const float*)d_in[14];
  float* outp = (float*)d_out;

  // workspace layout (~97.5 MB; 123 MB proven safe in round 1)
  char* ws = (char*)d_ws;
  unsigned short* aggb = (unsigned short*)ws;                    // 10240*2048*2 = 41,943,040
  unsigned short* h1   = (unsigned short*)(ws + 41943040);       // 10000*2048*2 = 40,960,000
  unsigned short* W2T  = (unsigned short*)(ws + 82903040);       // 2048*2048*2  =  8,388,608
  unsigned short* W3T  = (unsigned short*)(ws + 91291648);       // 1024*2048*2  =  4,194,304
  unsigned short* W1T  = (unsigned short*)(ws + 95485952);       // 2048*128*2   =    524,288
  int* cnt    = (int*)(ws + 96010240);
  int* off    = (int*)(ws + 96050240);
  int* cursor = (int*)(ws + 96090240);
  int* es     = (int*)(ws + 96130240);                           // ES_CAP*4 = 440,064
  float* rel  = (float*)(ws + 96570304);                         // ES_CAP*8 = 880,128
  // h2 bf16 [NN,2048] = 40,960,000 B lives in d_out; dead before GEMM3 overwrites it
  unsigned short* h2 = (unsigned short*)d_out;

  // 72 KiB dynamic LDS for gemm160 (host-side attribute; proven in round 7)
  hipFuncSetAttribute((const void*)gemm160<float>,
                      hipFuncAttributeMaxDynamicSharedMemorySize, 73728);

  const dim3 blk(256);
  const int eb = (NE + 255) / 256;
  const int ngb8 = ((NN + 15) / 16) * 8;   // 5000; gather_chunk grid = 2*ngb8

  // ---- CSR build (padded segments) + edge rel/src packing ----
  hipMemsetAsync(cnt, 0, NN * sizeof(int), stream);
  hipMemsetAsync(es, 0, ES_CAP * sizeof(int), stream);  // pad slots -> node 0 (safe addr)
  hist_kernel<<<eb, blk, 0, stream>>>(dstv, cnt);
  scan_kernel<<<1, 1024, 0, stream>>>(cnt, off, cursor);
  bucket_kernel<<<eb, blk, 0, stream>>>(srcv, dstv, pos, cursor, es, rel);

  // ---- fused weight transposes (one launch, 6400 tiles) ----
  transpose_w3<<<6400, blk, 0, stream>>>(Wout1, W1T, Wout2, W2T, Wout3, W3T);

  // zero the 240 pad rows of aggb once per call (gathers never touch them)
  hipMemsetAsync(aggb + (size_t)NN * 2048, 0, (size_t)(AGG_ROWS - NN) * 2048 * 2, stream);

  // ---- layer 1: 128 -> 2048 ----
  gather_l1<<<(NN + 3) / 4, blk, 0, stream>>>(x, off, cnt, es, rel, Win1, bin1, aggb);
  gemm320<unsigned short><<<dim3(2048 / 128, AGG_ROWS / 320), 512, 0, stream>>>(
      aggb, W1T, bout1, h1, NN, 2048, 128);

  // ---- layer 2: 2048 -> 2048 ----
  gather_chunk<<<2 * ngb8, blk, 0, stream>>>(h1, off, cnt, es, rel, Win2, bin2, aggb, ngb8);
  gemm320<unsigned short><<<dim3(2048 / 128, AGG_ROWS / 320), 512, 0, stream>>>(
      aggb, W2T, bout2, h2, NN, 2048, 2048);

  // ---- layer 3: 2048 -> 1024 (gemm160: 512 blocks = 2/CU, one exact round) ----
  gather_chunk<<<2 * ngb8, blk, 0, stream>>>(h2, off, cnt, es, rel, Win3, bin3, aggb, ngb8);
  gemm160<float><<<dim3(1024 / 128, AGG_ROWS / 160), blk, 73728, stream>>>(
      aggb, W3T, bout3, outp, NN, 1024, 2048);

  // ---- final L2 normalize ----
  l2norm_kernel<<<NN, blk, 0, stream>>>(outp);
}

// Round 18
// 300.557 us; speedup vs baseline: 1.0570x; 1.0288x over previous
//
#include <hip/hip_runtime.h>
#include <hip/hip_bf16.h>

#define DEVI __device__ __forceinline__

constexpr int NN = 10000;       // nodes
constexpr int NE = 80000;       // edges
constexpr int AGG_ROWS = 10240; // 32*320 and 64*160 — both M-tilings stay in-bounds
constexpr int ES_CAP = 110016;  // NE + 3*NN padded-CSR capacity, rounded up

typedef __attribute__((ext_vector_type(8))) short bf16x8;  // 8 bf16 (4 VGPRs)
typedef __attribute__((ext_vector_type(4))) float f32x4;   // MFMA acc

// ---------- bf16 helpers (bit-level, RNE) ----------
DEVI float blo(unsigned int u) {
  union { unsigned int i; float f; } c; c.i = u << 16; return c.f;
}
DEVI float bhi(unsigned int u) {
  union { unsigned int i; float f; } c; c.i = u & 0xffff0000u; return c.f;
}
DEVI unsigned short f2b(float f) {
  union { float f; unsigned int i; } c; c.f = f;
  unsigned int i = c.i;
  return (unsigned short)((i + 0x7fffu + ((i >> 16) & 1u)) >> 16);
}
DEVI void st1(float* p, float v) { *p = v; }
DEVI void st1(unsigned short* p, float v) { *p = f2b(v); }
DEVI void store8b(unsigned short* p, const float v[8]) {
  int4 pk;
  pk.x = (int)((unsigned)f2b(v[0]) | ((unsigned)f2b(v[1]) << 16));
  pk.y = (int)((unsigned)f2b(v[2]) | ((unsigned)f2b(v[3]) << 16));
  pk.z = (int)((unsigned)f2b(v[4]) | ((unsigned)f2b(v[5]) << 16));
  pk.w = (int)((unsigned)f2b(v[6]) | ((unsigned)f2b(v[7]) << 16));
  *reinterpret_cast<int4*>(p) = pk;
}

// async global->LDS, 16B per lane (wave-uniform LDS base + lane*16 pattern)
DEVI void gload16(const void* g, void* l) {
  __builtin_amdgcn_global_load_lds(
      (const __attribute__((address_space(1))) void*)g,
      (__attribute__((address_space(3))) void*)l, 16, 0, 0);
}

// ================= CSR build =================
__global__ __launch_bounds__(256)
void hist_kernel(const int* __restrict__ dst, int* __restrict__ cnt) {
  int e = blockIdx.x * 256 + threadIdx.x;
  if (e < NE) atomicAdd(&cnt[dst[e]], 1);
}

// exclusive scan of PADDED counts ((cnt+3)&~3) -> off, cursor.
__global__ __launch_bounds__(1024)
void scan_kernel(const int* __restrict__ cnt, int* __restrict__ off,
                 int* __restrict__ cursor) {
  __shared__ int wpart[16];
  __shared__ int carry;
  int tid = threadIdx.x, lane = tid & 63, w = tid >> 6;
  if (tid == 0) carry = 0;
  __syncthreads();
  for (int base = 0; base < NN; base += 1024) {
    int i = base + tid;
    int v = (i < NN) ? ((cnt[i] + 3) & ~3) : 0;
    int s = v;
#pragma unroll
    for (int o = 1; o < 64; o <<= 1) { int t = __shfl_up(s, o); if (lane >= o) s += t; }
    if (lane == 63) wpart[w] = s;
    __syncthreads();
    if (w == 0) {
      int ws = (lane < 16) ? wpart[lane] : 0;
#pragma unroll
      for (int o = 1; o < 16; o <<= 1) { int t = __shfl_up(ws, o); if (lane >= o) ws += t; }
      if (lane < 16) wpart[lane] = ws;
    }
    __syncthreads();
    int ex = carry + (w ? wpart[w - 1] : 0) + s - v;   // exclusive prefix
    if (i < NN) { off[i] = ex; cursor[i] = ex; }
    __syncthreads();
    if (tid == 0) carry += wpart[15];
    __syncthreads();
  }
}

// bucket: es[p] = src, rel[p] = pos[src]-pos[dst]. es pre-zeroed so pad slots
// hold node 0 (valid address); their FMAs are guarded off by cnt.
__global__ __launch_bounds__(256)
void bucket_kernel(const int* __restrict__ src, const int* __restrict__ dst,
                   const float* __restrict__ pos,
                   int* __restrict__ cursor, int* __restrict__ es,
                   float* __restrict__ rel) {
  int e = blockIdx.x * 256 + threadIdx.x;
  if (e < NE) {
    int s = src[e], d = dst[e];
    int p = atomicAdd(&cursor[d], 1);
    float2 ps = *reinterpret_cast<const float2*>(pos + 2 * s);
    float2 pd = *reinterpret_cast<const float2*>(pos + 2 * d);
    es[p] = s;
    *reinterpret_cast<float2*>(rel + 2 * p) = make_float2(ps.x - pd.x, ps.y - pd.y);
  }
}

// ==== fused weight convert+transpose: three W[K][N] f32 -> WT[N][K] bf16 ====
__global__ __launch_bounds__(256)
void transpose_w3(const float* __restrict__ W1, unsigned short* __restrict__ T1,
                  const float* __restrict__ W2, unsigned short* __restrict__ T2,
                  const float* __restrict__ W3, unsigned short* __restrict__ T3) {
  __shared__ float tile[32][33];
  int b = blockIdx.x;
  const float* W; unsigned short* WT; int K, N, bx, by;
  if (b < 256)        { W = W1; WT = T1; K = 128;  N = 2048; b -= 0;
                        bx = b & 63;  by = b >> 6; }   // 64 x 4
  else if (b < 4352)  { W = W2; WT = T2; K = 2048; N = 2048; b -= 256;
                        bx = b & 63;  by = b >> 6; }   // 64 x 64
  else                { W = W3; WT = T3; K = 2048; N = 1024; b -= 4352;
                        bx = b & 31;  by = b >> 5; }   // 32 x 64
  int tx = threadIdx.x & 31, ty = threadIdx.x >> 5;    // ty 0..7
  int n0 = bx * 32, k0 = by * 32;
#pragma unroll
  for (int j = 0; j < 32; j += 8)
    tile[ty + j][tx] = W[(size_t)(k0 + ty + j) * N + n0 + tx];
  __syncthreads();
#pragma unroll
  for (int j = 0; j < 32; j += 8)
    WT[(size_t)(n0 + ty + j) * K + k0 + tx] = f2b(tile[tx][ty + j]);
}

// ================= gather-aggregate (CSR, no atomics, int4 src fan-out) =================
// layer 1: C=128, x f32. One 64-lane wave per node, 2 ch/lane. bf16 out.
__global__ __launch_bounds__(256)
void gather_l1(const float* __restrict__ x,
               const int* __restrict__ off, const int* __restrict__ cnt,
               const int* __restrict__ es, const float* __restrict__ rel,
               const float* __restrict__ Win, const float* __restrict__ bin,
               unsigned short* __restrict__ agg) {
  constexpr int C = 128;
  int lane = threadIdx.x & 63;
  int i = blockIdx.x * 4 + (threadIdx.x >> 6);
  if (i >= NN) return;
  int c = lane * 2;
  float w00 = Win[c], w01 = Win[c + 1];
  float w10 = Win[C + c], w11 = Win[C + c + 1];
  float b0 = bin[c], b1 = bin[c + 1];
  float a0 = 0.f, a1 = 0.f;
  int s0 = off[i], n = cnt[i];   // s0 % 4 == 0 (padded CSR)

  for (int k = 0; k < n; k += 4) {
    int4 s4 = *reinterpret_cast<const int4*>(es + s0 + k);
    float4 ra = *reinterpret_cast<const float4*>(rel + 2 * (s0 + k));
    float4 rb = *reinterpret_cast<const float4*>(rel + 2 * (s0 + k) + 4);
    float2 q0 = *reinterpret_cast<const float2*>(x + (size_t)s4.x * C + c);
    float2 q1 = *reinterpret_cast<const float2*>(x + (size_t)s4.y * C + c);
    float2 q2 = *reinterpret_cast<const float2*>(x + (size_t)s4.z * C + c);
    float2 q3 = *reinterpret_cast<const float2*>(x + (size_t)s4.w * C + c);
    {
      float sc0 = fmaxf(fmaf(ra.x, w00, fmaf(ra.y, w10, b0)), 0.f);
      float sc1 = fmaxf(fmaf(ra.x, w01, fmaf(ra.y, w11, b1)), 0.f);
      a0 = fmaf(sc0, q0.x, a0); a1 = fmaf(sc1, q0.y, a1);
    }
    if (k + 1 < n) {
      float sc0 = fmaxf(fmaf(ra.z, w00, fmaf(ra.w, w10, b0)), 0.f);
      float sc1 = fmaxf(fmaf(ra.z, w01, fmaf(ra.w, w11, b1)), 0.f);
      a0 = fmaf(sc0, q1.x, a0); a1 = fmaf(sc1, q1.y, a1);
    }
    if (k + 2 < n) {
      float sc0 = fmaxf(fmaf(rb.x, w00, fmaf(rb.y, w10, b0)), 0.f);
      float sc1 = fmaxf(fmaf(rb.x, w01, fmaf(rb.y, w11, b1)), 0.f);
      a0 = fmaf(sc0, q2.x, a0); a1 = fmaf(sc1, q2.y, a1);
    }
    if (k + 3 < n) {
      float sc0 = fmaxf(fmaf(rb.z, w00, fmaf(rb.w, w10, b0)), 0.f);
      float sc1 = fmaxf(fmaf(rb.z, w01, fmaf(rb.w, w11, b1)), 0.f);
      a0 = fmaf(sc0, q3.x, a0); a1 = fmaf(sc1, q3.y, a1);
    }
  }
  unsigned int pk = (unsigned)f2b(a0) | ((unsigned)f2b(a1) << 16);
  *reinterpret_cast<unsigned int*>(agg + (size_t)i * C + c) = pk;
}

// layers 2/3: C=2048, 16 XCD-affine chunks of 128 ch. Block = 4 waves = 16
// node-slots; 16 lanes/node x 8 ch (16B loads). int4 src fan-out.
__global__ __launch_bounds__(256)
void gather_chunk(const unsigned short* __restrict__ x,
                  const int* __restrict__ off, const int* __restrict__ cnt,
                  const int* __restrict__ es, const float* __restrict__ rel,
                  const float* __restrict__ Win, const float* __restrict__ bin,
                  unsigned short* __restrict__ agg, int ngb8) {
  constexpr int C = 2048;
  constexpr int V = 8;
  int wgid = blockIdx.x;
  int half = wgid >= ngb8;
  int base = half ? wgid - ngb8 : wgid;
  int chunk = (base & 7) + (half << 3);     // 0..15
  int grp = base >> 3;                      // 0..624
  int lane = threadIdx.x & 63;
  int wid = threadIdx.x >> 6;
  int slot = lane >> 4;
  int l16 = lane & 15;
  int i = grp * 16 + wid * 4 + slot;        // 625*16 == 10000: always < NN
  int c = chunk * 128 + l16 * V;

  float w0[V], w1[V], bb[V], acc[V];
#pragma unroll
  for (int j = 0; j < V; ++j) {
    w0[j] = Win[c + j]; w1[j] = Win[C + c + j]; bb[j] = bin[c + j]; acc[j] = 0.f;
  }
  int s0 = off[i], n = cnt[i];   // s0 % 4 == 0 (padded CSR)

  auto fma8 = [&](float rx, float ry, const int4& q) {
    float xv[V] = { blo(q.x), bhi(q.x), blo(q.y), bhi(q.y),
                    blo(q.z), bhi(q.z), blo(q.w), bhi(q.w) };
#pragma unroll
    for (int j = 0; j < V; ++j) {
      float sc = fmaxf(fmaf(rx, w0[j], fmaf(ry, w1[j], bb[j])), 0.f);
      acc[j] = fmaf(sc, xv[j], acc[j]);
    }
  };
  for (int k = 0; k < n; k += 4) {
    int4 s4 = *reinterpret_cast<const int4*>(es + s0 + k);
    float4 ra = *reinterpret_cast<const float4*>(rel + 2 * (s0 + k));
    float4 rb = *reinterpret_cast<const float4*>(rel + 2 * (s0 + k) + 4);
    int4 q0 = *reinterpret_cast<const int4*>(x + (size_t)s4.x * C + c);
    int4 q1 = *reinterpret_cast<const int4*>(x + (size_t)s4.y * C + c);
    int4 q2 = *reinterpret_cast<const int4*>(x + (size_t)s4.z * C + c);
    int4 q3 = *reinterpret_cast<const int4*>(x + (size_t)s4.w * C + c);
    fma8(ra.x, ra.y, q0);
    if (k + 1 < n) fma8(ra.z, ra.w, q1);
    if (k + 2 < n) fma8(rb.x, rb.y, q2);
    if (k + 3 < n) fma8(rb.z, rb.w, q3);
  }
  store8b(agg + (size_t)i * C + c, acc);
}

// ===== 320x256 8-wave 4-phase MFMA GEMM, BK=64, PER-PHASE STAGE INTERLEAVE =====
// r14's gemm8p (refcheck'd) with ONLY the staging redistributed (m196 lever):
// per phase: {stage 2-3 gload passes into buf b^1 | ds_reads from buf b |
// barrier | setprio 20-MFMA setprio | barrier}; phase 1 additionally
// vmcnt(2) (own tile's 9 loads landed, 2 newest in flight — never 0 except
// last iter) + publish barrier BEFORE its reads. Per-thread FIFO invariant:
// 9 outstanding at every iteration boundary (2+2+2+3 staged per iter).
// Race ledger: stage targets buf b^1 whose last reads (tile kt-1, phase 4)
// completed via lgkmcnt before kt-1's trailing barrier; publish barrier
// follows counted vmcnt; all phase reads hit the published buffer.
// Grid: GEMM1/2 8x32 = 256 blocks = ONE exact round at 1 block/CU.
template <typename OT>
__global__ __launch_bounds__(512, 2)
void gemm4p(const unsigned short* __restrict__ A,
            const unsigned short* __restrict__ BT,
            const float* __restrict__ bias, OT* __restrict__ out,
            int M, int N, int K) {
  extern __shared__ unsigned short lds[];   // 2 bufs x 36864 ush (73728 B each)
  const int t = threadIdx.x;
  const int lane = t & 63, wid = t >> 6;    // 8 waves
  const int wr = wid >> 2, wc = wid & 3;    // 2M x 4N, wave-tile 160x64

  // XCD-chunked bijective swizzle (nwg % 8 == 0 for all our grids)
  const int nwg = gridDim.x * gridDim.y;
  const int orig = blockIdx.y * gridDim.x + blockIdx.x;
  const int swz = (orig & 7) * (nwg >> 3) + (orig >> 3);
  const int bx = swz % gridDim.x, by = swz / gridDim.x;
  const int m0 = by * 320, n0 = bx * 256;
  const int nk = K >> 6;

  // staging (r14-validated): pass = 64 rows x 8 slots (8KB, 512thr x 16B,
  // linear dest). thread t: row t>>3, slot t&7, source k-chunk = slot^(row&7).
  // passes 0-4: A rows p*64..; passes 5-8: B rows (p-5)*64..
  const int srow = t >> 3;                  // 0..63
  const int schunk = (t & 7) ^ (srow & 7);
  const unsigned short* gA = A + (size_t)(m0 + srow) * K + schunk * 8;
  const unsigned short* gB = BT + (size_t)(n0 + srow) * K + schunk * 8;
  const int lt8 = t * 8;                    // ush offset within pass

  auto PASS = [&](int buf, int kt, int j) {
    const size_t ko = (size_t)kt << 6;
    unsigned short* lb = lds + buf * 36864;
    if (j < 5)
      gload16(gA + (size_t)(j * 64) * K + ko, lb + j * 4096 + lt8);
    else
      gload16(gB + (size_t)((j - 5) * 64) * K + ko,
              lb + 20480 + (j - 5) * 4096 + lt8);
  };

  // fragment reads (r14 verbatim): row = base + m*16 + frow (bases ≡ 0 mod 8
  // -> swizzle lane-only); k-chunk = ks*4 + (lane>>4); slot = chunk^(frow&7);
  // ks=1 offset = ks=0 offset ^ 32.
  const int frow = lane & 15, kc = lane >> 4;
  const int sl0 = (kc ^ (frow & 7)) * 8;           // ush
  const int paRow = (wr * 160 + frow) * 64;        // + m*1024
  const int pbRow = 20480 + (wc * 64 + frow) * 64; // + n*1024

  f32x4 acc[10][4];
#pragma unroll
  for (int m = 0; m < 10; ++m)
#pragma unroll
    for (int n = 0; n < 4; ++n) acc[m][n] = 0.f;

  // prologue: stage all 9 passes of tile 0 into buf 0
#pragma unroll
  for (int j = 0; j < 9; ++j) PASS(0, 0, j);

  int cur = 0;
  for (int kt = 0; kt < nk; ++kt) {
    const bool pf = (kt + 1 < nk);
    const unsigned short* pa = lds + cur * 36864 + paRow;
    const unsigned short* pb = lds + cur * 36864 + pbRow;
    bf16x8 bf[4], af[5];

    // ---- phase 1: ks0, m0-4 (stage passes 0,1 | vmcnt(2) | publish) ----
    if (pf) {
      PASS(cur ^ 1, kt + 1, 0); PASS(cur ^ 1, kt + 1, 1);
      asm volatile("s_waitcnt vmcnt(2)" ::: "memory");
    } else {
      asm volatile("s_waitcnt vmcnt(0)" ::: "memory");
    }
    __builtin_amdgcn_s_barrier();                       // publish tile kt
#pragma unroll
    for (int n = 0; n < 4; ++n)
      bf[n] = *reinterpret_cast<const bf16x8*>(pb + n * 1024 + sl0);
#pragma unroll
    for (int m = 0; m < 5; ++m)
      af[m] = *reinterpret_cast<const bf16x8*>(pa + m * 1024 + sl0);
    __builtin_amdgcn_s_barrier();
    __builtin_amdgcn_s_setprio(1);
#pragma unroll
    for (int m = 0; m < 5; ++m)
#pragma unroll
      for (int n = 0; n < 4; ++n)
        acc[m][n] = __builtin_amdgcn_mfma_f32_16x16x32_bf16(
            af[m], bf[n], acc[m][n], 0, 0, 0);
    __builtin_amdgcn_s_setprio(0);
    __builtin_amdgcn_s_barrier();

    // ---- phase 2: ks0, m5-9 (stage passes 2,3) ----
    if (pf) { PASS(cur ^ 1, kt + 1, 2); PASS(cur ^ 1, kt + 1, 3); }
#pragma unroll
    for (int m = 0; m < 5; ++m)
      af[m] = *reinterpret_cast<const bf16x8*>(pa + (5 + m) * 1024 + sl0);
    __builtin_amdgcn_s_barrier();
    __builtin_amdgcn_s_setprio(1);
#pragma unroll
    for (int m = 0; m < 5; ++m)
#pragma unroll
      for (int n = 0; n < 4; ++n)
        acc[5 + m][n] = __builtin_amdgcn_mfma_f32_16x16x32_bf16(
            af[m], bf[n], acc[5 + m][n], 0, 0, 0);
    __builtin_amdgcn_s_setprio(0);
    __builtin_amdgcn_s_barrier();

    // ---- phase 3: ks1, m0-4 (stage passes 4,5) ----
    if (pf) { PASS(cur ^ 1, kt + 1, 4); PASS(cur ^ 1, kt + 1, 5); }
#pragma unroll
    for (int n = 0; n < 4; ++n)
      bf[n] = *reinterpret_cast<const bf16x8*>(pb + n * 1024 + (sl0 ^ 32));
#pragma unroll
    for (int m = 0; m < 5; ++m)
      af[m] = *reinterpret_cast<const bf16x8*>(pa + m * 1024 + (sl0 ^ 32));
    __builtin_amdgcn_s_barrier();
    __builtin_amdgcn_s_setprio(1);
#pragma unroll
    for (int m = 0; m < 5; ++m)
#pragma unroll
      for (int n = 0; n < 4; ++n)
        acc[m][n] = __builtin_amdgcn_mfma_f32_16x16x32_bf16(
            af[m], bf[n], acc[m][n], 0, 0, 0);
    __builtin_amdgcn_s_setprio(0);
    __builtin_amdgcn_s_barrier();

    // ---- phase 4: ks1, m5-9 (stage passes 6,7,8) ----
    if (pf) { PASS(cur ^ 1, kt + 1, 6); PASS(cur ^ 1, kt + 1, 7);
              PASS(cur ^ 1, kt + 1, 8); }
#pragma unroll
    for (int m = 0; m < 5; ++m)
      af[m] = *reinterpret_cast<const bf16x8*>(pa + (5 + m) * 1024 + (sl0 ^ 32));
    __builtin_amdgcn_s_barrier();
    __builtin_amdgcn_s_setprio(1);
#pragma unroll
    for (int m = 0; m < 5; ++m)
#pragma unroll
      for (int n = 0; n < 4; ++n)
        acc[5 + m][n] = __builtin_amdgcn_mfma_f32_16x16x32_bf16(
            af[m], bf[n], acc[5 + m][n], 0, 0, 0);
    __builtin_amdgcn_s_setprio(0);
    __builtin_amdgcn_s_barrier();   // trailing: buf cur fully read
    cur ^= 1;
  }

  // epilogue: C/D layout col=lane&15, row=(lane>>4)*4+reg
  const int ccol = lane & 15;
  const int crow = (lane >> 4) * 4;
  float bv[4];
#pragma unroll
  for (int n = 0; n < 4; ++n)
    bv[n] = bias[n0 + wc * 64 + n * 16 + ccol];
#pragma unroll
  for (int m = 0; m < 10; ++m) {
    int gm0 = m0 + wr * 160 + m * 16 + crow;
#pragma unroll
    for (int r = 0; r < 4; ++r) {
      int gm = gm0 + r;
      if (gm < M) {
        size_t base = (size_t)gm * N + n0 + wc * 64 + ccol;
#pragma unroll
        for (int n = 0; n < 4; ++n)
          st1(out + base + n * 16, fmaxf(acc[m][n][r] + bv[n], 0.f));
      }
    }
  }
}

// ============ 160x128 4-wave MFMA GEMM, BK=64 (round-7 proven, GEMM3) ============
template <typename OT>
__global__ __launch_bounds__(256, 2)
void gemm160(const unsigned short* __restrict__ A,
             const unsigned short* __restrict__ BT,
             const float* __restrict__ bias, OT* __restrict__ out,
             int M, int N, int K) {
  extern __shared__ unsigned short lds[];  // A: [2][10240] @0; B: [2][8192] @20480
  const int t = threadIdx.x;
  const int lane = t & 63, wid = t >> 6;
  const int wr = wid >> 1, wc = wid & 1;          // 2x2 wave grid, 80x64 each

  const int nwg = gridDim.x * gridDim.y;
  const int orig = blockIdx.y * gridDim.x + blockIdx.x;
  const int swz = (orig & 7) * (nwg >> 3) + (orig >> 3);
  const int bx = swz % gridDim.x, by = swz / gridDim.x;
  const int m0 = by * 160, n0 = bx * 128;
  const int nk = K >> 6;

  const int lrow = lane >> 3;              // 0..7
  const int schunk = (lane & 7) ^ lrow;    // pre-swizzled source k-chunk
  const unsigned short* gA = A + (size_t)(m0 + wid * 40 + lrow) * K + schunk * 8;
  const unsigned short* gB = BT + (size_t)(n0 + wid * 32 + lrow) * K + schunk * 8;
  unsigned short* lA = lds + (wid * 5) * 512 + lane * 8;          // +jj*512
  unsigned short* lB = lds + 20480 + (wid * 4) * 512 + lane * 8;  // +jj*512

  auto STAGE = [&](int buf, int kt) {
    const size_t ko = (size_t)kt << 6;
#pragma unroll
    for (int jj = 0; jj < 5; ++jj)
      gload16(gA + (size_t)(jj * 8) * K + ko, lA + buf * 10240 + jj * 512);
#pragma unroll
    for (int jj = 0; jj < 4; ++jj)
      gload16(gB + (size_t)(jj * 8) * K + ko, lB + buf * 8192 + jj * 512);
  };

  const int frow = lane & 15;
  const int fr7 = frow & 7;
  const int slot0 = ((lane >> 4) ^ fr7) * 8;        // ks=0
  const int slot1 = ((4 + (lane >> 4)) ^ fr7) * 8;  // ks=1
  const int paRow = (wr * 80 + frow) * 64;
  const int pbRow = (wc * 64 + frow) * 64;

  f32x4 acc[5][4];
#pragma unroll
  for (int m = 0; m < 5; ++m)
#pragma unroll
    for (int n = 0; n < 4; ++n) acc[m][n] = 0.f;

  STAGE(0, 0);  // prologue: 9 loads outstanding

  int cur = 0;
  for (int kt = 0; kt < nk; ++kt) {
    if (kt + 1 < nk) {
      STAGE(cur ^ 1, kt + 1);
      asm volatile("s_waitcnt vmcnt(9)" ::: "memory");  // kt's 9 loads landed
    } else {
      asm volatile("s_waitcnt vmcnt(0)" ::: "memory");
    }
    asm volatile("s_barrier" ::: "memory");  // all waves: tile kt staged
    const unsigned short* pa = lds + cur * 10240 + paRow;
    const unsigned short* pb = lds + 20480 + cur * 8192 + pbRow;
#pragma unroll
    for (int ks = 0; ks < 2; ++ks) {
      const int sl = ks ? slot1 : slot0;
      bf16x8 af[5], bf[4];
#pragma unroll
      for (int m = 0; m < 5; ++m)
        af[m] = *reinterpret_cast<const bf16x8*>(pa + m * 1024 + sl);
#pragma unroll
      for (int n = 0; n < 4; ++n)
        bf[n] = *reinterpret_cast<const bf16x8*>(pb + n * 1024 + sl);
      __builtin_amdgcn_s_setprio(1);
#pragma unroll
      for (int m = 0; m < 5; ++m)
#pragma unroll
        for (int n = 0; n < 4; ++n)
          acc[m][n] = __builtin_amdgcn_mfma_f32_16x16x32_bf16(
              af[m], bf[n], acc[m][n], 0, 0, 0);
      __builtin_amdgcn_s_setprio(0);
    }
    asm volatile("s_barrier" ::: "memory");  // reads done before overwrite
    cur ^= 1;
  }

  // epilogue: C/D layout col=lane&15, row=(lane>>4)*4+reg
  const int ccol = lane & 15;
  const int crow = (lane >> 4) * 4;
  float bv[4];
#pragma unroll
  for (int n = 0; n < 4; ++n)
    bv[n] = bias[n0 + wc * 64 + n * 16 + ccol];
#pragma unroll
  for (int m = 0; m < 5; ++m) {
    int gm0 = m0 + wr * 80 + m * 16 + crow;
#pragma unroll
    for (int r = 0; r < 4; ++r) {
      int gm = gm0 + r;
      if (gm < M) {
        size_t base = (size_t)gm * N + n0 + wc * 64 + ccol;
#pragma unroll
        for (int n = 0; n < 4; ++n)
          st1(out + base + n * 16, fmaxf(acc[m][n][r] + bv[n], 0.f));
      }
    }
  }
}

// ---------- row-wise L2 normalize, C=1024 ----------
__global__ __launch_bounds__(256)
void l2norm_kernel(float* __restrict__ out) {
  constexpr int C = 1024;
  float* p = out + (size_t)blockIdx.x * C;
  float4 v = *reinterpret_cast<const float4*>(p + threadIdx.x * 4);
  float s = v.x * v.x + v.y * v.y + v.z * v.z + v.w * v.w;
#pragma unroll
  for (int o = 32; o > 0; o >>= 1) s += __shfl_down(s, o);
  __shared__ float wsum[4];
  if ((threadIdx.x & 63) == 0) wsum[threadIdx.x >> 6] = s;
  __syncthreads();
  float tot = wsum[0] + wsum[1] + wsum[2] + wsum[3];
  float inv = 1.0f / fmaxf(sqrtf(tot), 1e-12f);
  float4 r = make_float4(v.x * inv, v.y * inv, v.z * inv, v.w * inv);
  *reinterpret_cast<float4*>(p + threadIdx.x * 4) = r;
}

extern "C" void kernel_launch(void* const* d_in, const int* in_sizes, int n_in,
                              void* d_out, int out_size, void* d_ws, size_t ws_size,
                              hipStream_t stream) {
  (void)in_sizes; (void)n_in; (void)out_size; (void)ws_size;
  const float* x     = (const float*)d_in[0];
  const float* pos   = (const float*)d_in[1];
  const int*   ei    = (const int*)d_in[2];
  const int*   srcv  = ei;            // edge_index[0] (j)
  const int*   dstv  = ei + NE;       // edge_index[1] (i)
  const float* Win1  = (const float*)d_in[3];
  const float* bin1  = (const float*)d_in[4];
  const float* Wout1 = (const float*)d_in[5];
  const float* bout1 = (const float*)d_in[6];
  const float* Win2  = (const float*)d_in[7];
  const float* bin2  = (const float*)d_in[8];
  const float* Wout2 = (const float*)d_in[9];
  const float* bout2 = (const float*)d_in[10];
  const float* Win3  = (const float*)d_in[11];
  const float* bin3  = (const float*)d_in[12];
  const float* Wout3 = (const float*)d_in[13];
  const float* bout3 = (const float*)d_in[14];
  float* outp = (float*)d_out;

  // workspace layout (~97.5 MB; 123 MB proven safe in round 1)
  char* ws = (char*)d_ws;
  unsigned short* aggb = (unsigned short*)ws;                    // 10240*2048*2 = 41,943,040
  unsigned short* h1   = (unsigned short*)(ws + 41943040);       // 10000*2048*2 = 40,960,000
  unsigned short* W2T  = (unsigned short*)(ws + 82903040);       // 2048*2048*2  =  8,388,608
  unsigned short* W3T  = (unsigned short*)(ws + 91291648);       // 1024*2048*2  =  4,194,304
  unsigned short* W1T  = (unsigned short*)(ws + 95485952);       // 2048*128*2   =    524,288
  int* cnt    = (int*)(ws + 96010240);
  int* off    = (int*)(ws + 96050240);
  int* cursor = (int*)(ws + 96090240);
  int* es     = (int*)(ws + 96130240);                           // ES_CAP*4 = 440,064
  float* rel  = (float*)(ws + 96570304);                         // ES_CAP*8 = 880,128
  // h2 bf16 [NN,2048] = 40,960,000 B lives in d_out; dead before GEMM3 overwrites it
  unsigned short* h2 = (unsigned short*)d_out;

  // dynamic LDS attributes (host-side, graph-capture safe, proven round 3)
  hipFuncSetAttribute((const void*)gemm4p<unsigned short>,
                      hipFuncAttributeMaxDynamicSharedMemorySize, 147456);
  hipFuncSetAttribute((const void*)gemm160<float>,
                      hipFuncAttributeMaxDynamicSharedMemorySize, 73728);

  const dim3 blk(256);
  const int eb = (NE + 255) / 256;
  const int ngb8 = ((NN + 15) / 16) * 8;   // 5000; gather_chunk grid = 2*ngb8

  // ---- CSR build (padded segments) + edge rel/src packing ----
  hipMemsetAsync(cnt, 0, NN * sizeof(int), stream);
  hipMemsetAsync(es, 0, ES_CAP * sizeof(int), stream);  // pad slots -> node 0 (safe addr)
  hist_kernel<<<eb, blk, 0, stream>>>(dstv, cnt);
  scan_kernel<<<1, 1024, 0, stream>>>(cnt, off, cursor);
  bucket_kernel<<<eb, blk, 0, stream>>>(srcv, dstv, pos, cursor, es, rel);

  // ---- fused weight transposes (one launch, 6400 tiles) ----
  transpose_w3<<<6400, blk, 0, stream>>>(Wout1, W1T, Wout2, W2T, Wout3, W3T);

  // zero the 240 pad rows of aggb once per call (gathers never touch them)
  hipMemsetAsync(aggb + (size_t)NN * 2048, 0, (size_t)(AGG_ROWS - NN) * 2048 * 2, stream);

  // ---- layer 1: 128 -> 2048 ----
  gather_l1<<<(NN + 3) / 4, blk, 0, stream>>>(x, off, cnt, es, rel, Win1, bin1, aggb);
  gemm4p<unsigned short><<<dim3(2048 / 256, AGG_ROWS / 320), 512, 147456, stream>>>(
      aggb, W1T, bout1, h1, NN, 2048, 128);

  // ---- layer 2: 2048 -> 2048 ----
  gather_chunk<<<2 * ngb8, blk, 0, stream>>>(h1, off, cnt, es, rel, Win2, bin2, aggb, ngb8);
  gemm4p<unsigned short><<<dim3(2048 / 256, AGG_ROWS / 320), 512, 147456, stream>>>(
      aggb, W2T, bout2, h2, NN, 2048, 2048);

  // ---- layer 3: 2048 -> 1024 (gemm160: 512 blocks = 2/CU, one exact round) ----
  gather_chunk<<<2 * ngb8, blk, 0, stream>>>(h2, off, cnt, es, rel, Win3, bin3, aggb, ngb8);
  gemm160<float><<<dim3(1024 / 128, AGG_ROWS / 160), blk, 73728, stream>>>(
      aggb, W3T, bout3, outp, NN, 1024, 2048);

  // ---- final L2 normalize ----
  l2norm_kernel<<<NN, blk, 0, stream>>>(outp);
}